// Round 7
// baseline (22913.493 us; speedup 1.0000x reference)
//
#include <hip/hip_runtime.h>
#include <hip/hip_cooperative_groups.h>
#include <hip/hip_fp16.h>

namespace cg = cooperative_groups;

#define TSTEP 128
#define LATD 256

// ---------------------------------------------------------------------------
// R14: full-K blocks, 4 phases/step, zero partial traffic.
// R13 post-mortem: nt stores BROKE part's producer->consumer L2 reuse (FETCH
// up, dur up); flag-array barrier polls 256 lines/block vs tree's 1 (fabric
// storm). Both reverted (tree barrier + plain sc1 stores = R12, 12.29 ms).
// R14 removes the ~60 us/step of barrier+part overhead structurally:
//  - GRU: 256 blocks x 4 hidden units; block owns 24 wcols (4u x 3gates x
//    {x,h}) over full K=1024. Acts staged fp32 in 8x128-row chunks (x+h);
//    threads = part(2) x ksub(16, K-stride-16) x mq(16); 48 acc, same
//    b128+b64 fp16-weight inner loop as R12. LDS reduce (stride-769 padded)
//    -> gates applied inline -> h' written direct. No part, no comb.
//  - p5 (5 cols: WhW1|Wh split, bias+relu->t1, tail->out) and p6 (4 cols,
//    ->gin) same full-K structure (ksub 32, strides 321/257).
//  - 4 fastbars/step (was 8). h1/h2 double-buffered (race-free full-K
//    read-then-write), buffers carved from the now-free part region.
// Folds (verified R3-R13): Wvoih=(Wv@Wo)@Wih0, bfold=(bv@Wo+bo)@Wih0+bih0,
// WhW1=Wh@w1, bhw1=bh@w1+b1.
// ---------------------------------------------------------------------------

typedef __attribute__((ext_vector_type(2))) unsigned long long u64x2;

struct P {
  const float *z, *w1, *b1, *w2, *b2, *Wv, *bv, *Wo, *bo;
  const float *Wih0, *Whh0, *bih0, *bhh0, *Wih1, *Whh1, *bih1, *bhh1, *Wh, *bh;
  float *out;
  __half *Wvoihh, *Whh0h, *Wih1h, *Whh1h, *WhW1h, *Whh, *w2h;
  float *part, *gin, *h1, *h2, *h1b, *h2b, *t1, *bvo, *bfold, *bhw1;
  unsigned *bar;   // leaves at i*32 (i<16), root at 512, flag at 544
};

__device__ __forceinline__ float ald(const float* p) {
  return __hip_atomic_load((float*)p, __ATOMIC_RELAXED, __HIP_MEMORY_SCOPE_AGENT);
}
__device__ __forceinline__ void ast(float* p, float v) {
  __hip_atomic_store(p, v, __ATOMIC_RELAXED, __HIP_MEMORY_SCOPE_AGENT);
}
__device__ __forceinline__ unsigned long long ald64(const unsigned long long* p) {
  return __hip_atomic_load((unsigned long long*)p, __ATOMIC_RELAXED,
                           __HIP_MEMORY_SCOPE_AGENT);
}

__device__ __forceinline__ unsigned long long f4h4(float4 v) {
  union { unsigned long long q; __half h[4]; } c;
  c.h[0] = __float2half(v.x); c.h[1] = __float2half(v.y);
  c.h[2] = __float2half(v.z); c.h[3] = __float2half(v.w);
  return c.q;
}

// Fence-free hierarchical grid barrier (R7-proven; R12 version).
__device__ __forceinline__ void fastbar(unsigned* bar, unsigned& ep) {
  ++ep;
  __atomic_signal_fence(__ATOMIC_SEQ_CST);
  __builtin_amdgcn_s_waitcnt(0);
  __atomic_signal_fence(__ATOMIC_SEQ_CST);
  __syncthreads();
  if (threadIdx.x == 0) {
    unsigned* leaf = bar + (blockIdx.x & 15u) * 32u;
    unsigned a = atomicAdd(leaf, 1u);
    if (a == ep * 16u - 1u) {
      unsigned r = atomicAdd(bar + 512, 1u);
      if (r == ep * 16u - 1u)
        __hip_atomic_store(bar + 544, ep, __ATOMIC_RELAXED, __HIP_MEMORY_SCOPE_AGENT);
    }
    while (__hip_atomic_load(bar + 544, __ATOMIC_RELAXED, __HIP_MEMORY_SCOPE_AGENT) < ep)
      __builtin_amdgcn_s_sleep(1);
  }
  __syncthreads();
}

// ---- prologue helpers (256 blocks x 512 threads) --------------------------
__device__ __forceinline__ void stv(float* p, float v) { *p = v; }
__device__ __forceinline__ void stv(__half* p, float v) { *p = __float2half(v); }

template <int J, int N, int CPT, typename OT>
__device__ void matmat(const float* __restrict__ A, const float* __restrict__ B,
                       OT* __restrict__ C) {
  const int tid = threadIdx.x;
  const int r = blockIdx.x * 4 + (tid >> 7);
  const int c0 = tid & 127;
  float acc[CPT];
#pragma unroll
  for (int i = 0; i < CPT; ++i) acc[i] = 0.f;
  const float* ar = A + (size_t)r * J;
#pragma unroll 2
  for (int j = 0; j < J; ++j) {
    float av = ar[j];
    const float* br = B + (size_t)j * N + c0;
#pragma unroll
    for (int i = 0; i < CPT; ++i) acc[i] = fmaf(av, br[i * 128], acc[i]);
  }
  OT* cr = C + (size_t)r * N + c0;
#pragma unroll
  for (int i = 0; i < CPT; ++i) stv(cr + (size_t)i * 128, acc[i]);
}

__device__ void cvt_copy(const float* __restrict__ s, __half* __restrict__ d,
                         int n4) {
  for (int i = (int)(blockIdx.x * 512u + threadIdx.x); i < n4; i += 131072)
    *(unsigned long long*)(d + (size_t)i * 4) = f4h4(*(const float4*)(s + (size_t)i * 4));
}

__device__ void vecmat(const float* __restrict__ v, const float* __restrict__ M,
                       const float* __restrict__ badd, float* __restrict__ outv,
                       int J, int N, int blk0, int nblk) {
  int b = (int)blockIdx.x;
  if (b < blk0 || b >= blk0 + nblk) return;
  int gid = (b - blk0) * 512 + threadIdx.x;
  if (gid >= N) return;
  float acc = 0.f;
#pragma unroll 4
  for (int j = 0; j < J; ++j) acc = fmaf(v[j], M[(size_t)j * N + gid], acc);
  outv[gid] = acc + badd[gid];
}

__device__ void gemv1024(const float* __restrict__ A, const float* __restrict__ W,
                         const float* __restrict__ bias, int K, int relu,
                         float* __restrict__ C, float* __restrict__ C2,
                         float* __restrict__ C3, float* red) {
  const int tid = threadIdx.x;
  const int m = tid & 63, w = tid >> 6;
  const int j = w & 3, hh = w >> 2;
  const int c = blockIdx.x * 4 + j;
  const int kh = K >> 1;
  const float* a = A + m + (hh * kh) * 64;
  const float* wp = W + c + (size_t)(hh * kh) * 1024;
  float acc = 0.f;
#pragma unroll 8
  for (int k = 0; k < kh; ++k) acc = fmaf(a[k * 64], wp[(size_t)k * 1024], acc);
  if (hh) red[j * 64 + m] = acc;
  __syncthreads();
  if (!hh) {
    float v = acc + red[j * 64 + m] + bias[c];
    if (relu) v = fmaxf(v, 0.f);
    C[c * 64 + m] = v;
    if (C2) C2[c * 64 + m] = v;
    if (C3) C3[c * 64 + m] = v;
  }
  __syncthreads();
}

// ---- GRU phase (full-K): block owns 4 hidden units ------------------------
// Threads: p = tid>>8 (0:x-part, 1:h-part); ks = (tid>>4)&15 (K stride-16);
// mq = tid&15 (4 m). Per chunk (128 rows): stage xa[128][64]f32 @0,
// ha @8192, wx[128][16]h @16384f, wh @17408f. FMA: 8 rows/thread/chunk,
// act b128 + w b128 + w b64 -> 48 FMA. Epilogue: 32 regions stride 769
// (@0, acts dead), sum -> gsum[1536] @24608, gates -> h' direct.
__device__ __forceinline__ void gru_phase(const __half* __restrict__ Wx,
                                          const __half* __restrict__ Wh,
                                          const float* __restrict__ actx,
                                          const float* __restrict__ acth,
                                          const float* __restrict__ bx,
                                          const float* __restrict__ bm,
                                          const float* __restrict__ hprev,
                                          float* __restrict__ hnew,
                                          float* __restrict__ sm) {
  const int tid = threadIdx.x;
  const int u0 = (int)blockIdx.x * 4;
  unsigned long long* smq = (unsigned long long*)sm;

  const int p = tid >> 8;
  const int idx = tid & 255;
  const int ks = idx >> 4, mq = idx & 15;

  float acc[48];
#pragma unroll
  for (int j = 0; j < 48; ++j) acc[j] = 0.f;

  const float* ap = sm + (size_t)p * 8192 + mq * 4;
  const __half* wp8 = (const __half*)(sm + 16384 + p * 1024);

  for (int c = 0; c < 8; ++c) {
    const int k0 = c * 128;
    {  // acts: 4096 u64 each
      const unsigned long long* Xq = (const unsigned long long*)(actx + (size_t)k0 * 64);
      const unsigned long long* Hq = (const unsigned long long*)(acth + (size_t)k0 * 64);
#pragma unroll
      for (int r = 0; r < 8; ++r) smq[tid + r * 512] = ald64(Xq + tid + r * 512);
#pragma unroll
      for (int r = 0; r < 8; ++r) smq[4096 + tid + r * 512] = ald64(Hq + tid + r * 512);
    }
    {  // weights: 768 b64 loads (slot = which plane/gate-group, row)
#pragma unroll
      for (int r = 0; r < 2; ++r) {
        int i2 = tid + r * 512;
        if (i2 < 768) {
          int slot = i2 >> 7, row = i2 & 127;
          int grp = slot < 3 ? slot : slot - 3;
          const __half* src = (slot < 3 ? Wx : Wh) +
                              (size_t)(k0 + row) * 3072 + grp * 1024 + u0;
          smq[(slot < 3 ? 8192 : 8704) + row * 4 + grp] =
              *(const unsigned long long*)src;
        }
      }
    }
    __syncthreads();
#pragma unroll 2
    for (int i = 0; i < 8; ++i) {
      const int lr = ks + i * 16;
      float4 a4 = *(const float4*)(ap + (size_t)lr * 64);
      union { u64x2 v; __half h[8]; } ua;
      ua.v = *(const u64x2*)(wp8 + lr * 16);
      union { unsigned long long v; __half h[4]; } ub;
      ub.v = *(const unsigned long long*)(wp8 + lr * 16 + 8);
#pragma unroll
      for (int cc = 0; cc < 8; ++cc) {
        float wf = __half2float(ua.h[cc]);
        acc[cc * 4 + 0] = fmaf(a4.x, wf, acc[cc * 4 + 0]);
        acc[cc * 4 + 1] = fmaf(a4.y, wf, acc[cc * 4 + 1]);
        acc[cc * 4 + 2] = fmaf(a4.z, wf, acc[cc * 4 + 2]);
        acc[cc * 4 + 3] = fmaf(a4.w, wf, acc[cc * 4 + 3]);
      }
#pragma unroll
      for (int cc = 0; cc < 4; ++cc) {
        float wf = __half2float(ub.h[cc]);
        acc[32 + cc * 4 + 0] = fmaf(a4.x, wf, acc[32 + cc * 4 + 0]);
        acc[32 + cc * 4 + 1] = fmaf(a4.y, wf, acc[32 + cc * 4 + 1]);
        acc[32 + cc * 4 + 2] = fmaf(a4.z, wf, acc[32 + cc * 4 + 2]);
        acc[32 + cc * 4 + 3] = fmaf(a4.w, wf, acc[32 + cc * 4 + 3]);
      }
    }
    __syncthreads();
  }
  // ---- reduce: 32 regions stride 769 (bank-walk 1) ----
  {
    float* rp = sm + (size_t)(p * 16 + ks) * 769 + mq * 4;
#pragma unroll
    for (int cc = 0; cc < 8; ++cc)
      *(float4*)(rp + (size_t)cc * 64) =
          make_float4(acc[cc * 4], acc[cc * 4 + 1], acc[cc * 4 + 2], acc[cc * 4 + 3]);
#pragma unroll
    for (int cc = 0; cc < 4; ++cc)
      *(float4*)(rp + (size_t)(8 + cc) * 64) =
          make_float4(acc[32 + cc * 4], acc[32 + cc * 4 + 1],
                      acc[32 + cc * 4 + 2], acc[32 + cc * 4 + 3]);
  }
  __syncthreads();
  float* gsum = sm + 24608;
#pragma unroll
  for (int j = 0; j < 3; ++j) {
    int q = tid * 3 + j;             // 0..1535
    int pp = (q >= 768) ? 1 : 0;
    int rem = q - pp * 768;
    const float* rr = sm + (size_t)pp * 16 * 769 + rem;
    float v = 0.f;
#pragma unroll
    for (int k2 = 0; k2 < 16; ++k2) v += rr[(size_t)k2 * 769];
    gsum[q] = v;
  }
  __syncthreads();
  if (tid < 256) {
    const int cu = tid >> 6, m = tid & 63;
    const int u = u0 + cu;
    float rx = gsum[cu * 64 + m];
    float zx = gsum[(4 + cu) * 64 + m];
    float nx = gsum[(8 + cu) * 64 + m];
    float rh = gsum[768 + cu * 64 + m];
    float zh = gsum[768 + (4 + cu) * 64 + m];
    float nh = gsum[768 + (8 + cu) * 64 + m];
    float r  = 1.f / (1.f + expf(-(rx + rh + bx[u] + bm[u])));
    float zg = 1.f / (1.f + expf(-(zx + zh + bx[1024 + u] + bm[1024 + u])));
    float nn = tanhf(nx + bx[2048 + u] + r * (nh + bm[2048 + u]));
    float hp = ald(hprev + (size_t)u * 64 + m);
    ast(hnew + (size_t)u * 64 + m, (1.f - zg) * nn + zg * hp);
  }
}

// ---- P5 (full-K): block owns 5 cols of [WhW1|Wh] --------------------------
// ks = tid>>4 (32, K stride-32), mq = tid&15. Chunk: act[128][64] @0,
// w[128][8]h @8192f. 20 acc. Reduce 32 regions stride 321; sum threads
// (320) apply bias + relu->t1 or ->out.
__device__ __forceinline__ void p5_phase(const __half* __restrict__ WhW1,
                                         const __half* __restrict__ Whd,
                                         const float* __restrict__ h2,
                                         const float* __restrict__ bhw1,
                                         const float* __restrict__ bh,
                                         float* __restrict__ t1,
                                         float* __restrict__ out, int t,
                                         float* __restrict__ sm) {
  const int tid = threadIdx.x;
  const int c0 = (int)blockIdx.x * 5;
  unsigned long long* smq = (unsigned long long*)sm;
  const int ks = tid >> 4, mq = tid & 15;
  float acc[20];
#pragma unroll
  for (int j = 0; j < 20; ++j) acc[j] = 0.f;
  const float* ap = sm + mq * 4;
  const __half* wp8 = (const __half*)(sm + 8192);

  for (int c = 0; c < 8; ++c) {
    const int k0 = c * 128;
    {
      const unsigned long long* Aq = (const unsigned long long*)(h2 + (size_t)k0 * 64);
#pragma unroll
      for (int r = 0; r < 8; ++r) smq[tid + r * 512] = ald64(Aq + tid + r * 512);
    }
    {  // 640 scalar half loads
#pragma unroll
      for (int r = 0; r < 2; ++r) {
        int i2 = tid + r * 512;
        if (i2 < 640) {
          int col = i2 >> 7, row = i2 & 127;
          int gc = c0 + col;
          __half v = (gc < 1024) ? WhW1[(size_t)(k0 + row) * 1024 + gc]
                                 : Whd[(size_t)(k0 + row) * 256 + (gc - 1024)];
          ((__half*)(sm + 8192))[row * 8 + col] = v;
        }
      }
    }
    __syncthreads();
#pragma unroll
    for (int i = 0; i < 4; ++i) {
      const int lr = ks + i * 32;
      float4 a4 = *(const float4*)(ap + (size_t)lr * 64);
      union { u64x2 v; __half h[8]; } uw;
      uw.v = *(const u64x2*)(wp8 + lr * 8);
#pragma unroll
      for (int cc = 0; cc < 5; ++cc) {
        float wf = __half2float(uw.h[cc]);
        acc[cc * 4 + 0] = fmaf(a4.x, wf, acc[cc * 4 + 0]);
        acc[cc * 4 + 1] = fmaf(a4.y, wf, acc[cc * 4 + 1]);
        acc[cc * 4 + 2] = fmaf(a4.z, wf, acc[cc * 4 + 2]);
        acc[cc * 4 + 3] = fmaf(a4.w, wf, acc[cc * 4 + 3]);
      }
    }
    __syncthreads();
  }
  {
    float* rp = sm + (size_t)ks * 321 + mq * 4;
#pragma unroll
    for (int cc = 0; cc < 5; ++cc)
      *(float4*)(rp + (size_t)cc * 64) =
          make_float4(acc[cc * 4], acc[cc * 4 + 1], acc[cc * 4 + 2], acc[cc * 4 + 3]);
  }
  __syncthreads();
  if (tid < 320) {
    const int cc = tid >> 6, m = tid & 63;
    float v = 0.f;
#pragma unroll
    for (int k2 = 0; k2 < 32; ++k2) v += sm[(size_t)k2 * 321 + cc * 64 + m];
    const int gc = c0 + cc;
    if (gc < 1024) {
      ast(t1 + (size_t)gc * 64 + m, fmaxf(v + bhw1[gc], 0.f));
    } else {
      out[(size_t)(m * TSTEP + t) * LATD + (gc - 1024)] = v + bh[gc - 1024];
    }
  }
}

// ---- P6 (full-K): block owns 4 cols of w2 ---------------------------------
__device__ __forceinline__ void p6_phase(const __half* __restrict__ w2h,
                                         const float* __restrict__ t1,
                                         const float* __restrict__ b2,
                                         float* __restrict__ gin,
                                         float* __restrict__ sm) {
  const int tid = threadIdx.x;
  const int c0 = (int)blockIdx.x * 4;
  unsigned long long* smq = (unsigned long long*)sm;
  const int ks = tid >> 4, mq = tid & 15;
  float acc[16];
#pragma unroll
  for (int j = 0; j < 16; ++j) acc[j] = 0.f;
  const float* ap = sm + mq * 4;
  const __half* wp8 = (const __half*)(sm + 8192);

  for (int c = 0; c < 8; ++c) {
    const int k0 = c * 128;
    {
      const unsigned long long* Aq = (const unsigned long long*)(t1 + (size_t)k0 * 64);
#pragma unroll
      for (int r = 0; r < 8; ++r) smq[tid + r * 512] = ald64(Aq + tid + r * 512);
    }
    if (tid < 128)
      smq[4096 + tid] =
          *(const unsigned long long*)(w2h + (size_t)(k0 + tid) * 1024 + c0);
    __syncthreads();
#pragma unroll
    for (int i = 0; i < 4; ++i) {
      const int lr = ks + i * 32;
      float4 a4 = *(const float4*)(ap + (size_t)lr * 64);
      union { unsigned long long v; __half h[4]; } uw;
      uw.v = *(const unsigned long long*)(wp8 + lr * 4);
#pragma unroll
      for (int cc = 0; cc < 4; ++cc) {
        float wf = __half2float(uw.h[cc]);
        acc[cc * 4 + 0] = fmaf(a4.x, wf, acc[cc * 4 + 0]);
        acc[cc * 4 + 1] = fmaf(a4.y, wf, acc[cc * 4 + 1]);
        acc[cc * 4 + 2] = fmaf(a4.z, wf, acc[cc * 4 + 2]);
        acc[cc * 4 + 3] = fmaf(a4.w, wf, acc[cc * 4 + 3]);
      }
    }
    __syncthreads();
  }
  {
    float* rp = sm + (size_t)ks * 257 + mq * 4;
#pragma unroll
    for (int cc = 0; cc < 4; ++cc)
      *(float4*)(rp + (size_t)cc * 64) =
          make_float4(acc[cc * 4], acc[cc * 4 + 1], acc[cc * 4 + 2], acc[cc * 4 + 3]);
  }
  __syncthreads();
  if (tid < 256) {
    const int cc = tid >> 6, m = tid & 63;
    float v = 0.f;
#pragma unroll
    for (int k2 = 0; k2 < 32; ++k2) v += sm[(size_t)k2 * 257 + cc * 64 + m];
    const int gc = c0 + cc;
    ast(gin + (size_t)gc * 64 + m, fmaxf(v + b2[gc], 0.f));
  }
}

__global__ __launch_bounds__(512, 1) void persist(P p) {
  cg::grid_group grid = cg::this_grid();
  // 112 KB. GRU: xa 0-8191 | ha 8192-16383 | wx 16384-17407 | wh 17408-18431;
  // reduce 32x769=24608 @0 (acts dead); gsum 24608-26143. p5: act 8192 +
  // w 512 @8192; reduce 32x321 @0. p6: act + w(256f) @8192; reduce 32x257.
  __shared__ float sm[28672];
  unsigned ep = 0;

  // ---- prologue (4 slow cg syncs flush prologue's normal stores) ----
  if (blockIdx.x == 0) {
    for (int i = threadIdx.x; i < 1024; i += 512) p.bar[i] = 0u;
  }
  if (threadIdx.x < 64) {  // z transpose -> h1 region (consumed pre-overwrite)
    int i = blockIdx.x * 64 + threadIdx.x;
    int m = i >> 8, l = i & 255;
    p.h1[l * 64 + m] = p.z[i];
  }
  matmat<1024, 1024, 8>(p.Wv, p.Wo, p.part);            // Wvo (fp32 temp)
  vecmat(p.bh, p.w1, p.b1, p.bhw1, 256, 1024, 0, 2);
  vecmat(p.bv, p.Wo, p.bo, p.bvo, 1024, 1024, 2, 2);
  cvt_copy(p.Whh0, p.Whh0h, 786432);                    // raw weights -> fp16
  cvt_copy(p.Wih1, p.Wih1h, 786432);
  cvt_copy(p.Whh1, p.Whh1h, 786432);
  cvt_copy(p.w2,   p.w2h,   262144);
  cvt_copy(p.Wh,   p.Whh,   65536);
  grid.sync();
  matmat<1024, 3072, 24>(p.part, p.Wih0, p.Wvoihh);     // Wvoih -> fp16 direct
  matmat<256, 1024, 8>(p.Wh, p.w1, p.WhW1h);            // WhW1 -> fp16 direct
  vecmat(p.bvo, p.Wih0, p.bih0, p.bfold, 1024, 3072, 0, 6);
  grid.sync();
  gemv1024(p.h1, p.w1, p.b1, 256, 1, p.t1, nullptr, nullptr, sm);
  grid.sync();
  gemv1024(p.t1, p.w2, p.b2, 1024, 0, p.h1, p.h2, p.gin, sm);
  grid.sync();

  // ---- time loop: 4 fence-free phases/step ----
  for (int t = 0; t < TSTEP; ++t) {
    float* h1c = (t & 1) ? p.h1b : p.h1;
    float* h1n = (t & 1) ? p.h1 : p.h1b;
    float* h2c = (t & 1) ? p.h2b : p.h2;
    float* h2n = (t & 1) ? p.h2 : p.h2b;
    gru_phase(p.Wvoihh, p.Whh0h, p.gin, h1c, p.bfold, p.bhh0, h1c, h1n, sm);
    fastbar(p.bar, ep);
    gru_phase(p.Wih1h, p.Whh1h, h1n, h2c, p.bih1, p.bhh1, h2c, h2n, sm);
    fastbar(p.bar, ep);
    p5_phase(p.WhW1h, p.Whh, h2n, p.bhw1, p.bh, p.t1, p.out, t, sm);
    fastbar(p.bar, ep);
    p6_phase(p.w2h, p.t1, p.b2, p.gin, sm);
    fastbar(p.bar, ep);
  }
}

// ---------------------------------------------------------------------------
// Fallback path (round-2 verified multi-kernel, fp32 — unchanged).
// ---------------------------------------------------------------------------
__global__ void fb_transpose(const float* __restrict__ z, float* __restrict__ zT) {
  int i = blockIdx.x * 256 + threadIdx.x;
  int m = i >> 8, l = i & 255;
  zT[l * 64 + m] = z[i];
}
__global__ void fb_copy2(const float* __restrict__ s, float* __restrict__ d1,
                         float* __restrict__ d2) {
  int i = blockIdx.x * 256 + threadIdx.x;
  float v = s[i]; d1[i] = v; d2[i] = v;
}
template <int ACT>
__global__ void fb_gemm(const float* __restrict__ A_T, const float* __restrict__ W,
                        const float* __restrict__ bias, float* __restrict__ C_T,
                        int K, int N, float* __restrict__ outp, int tstep) {
  const int m = threadIdx.x & 63;
  const int wv = threadIdx.x >> 6;
  const int c = blockIdx.x * 4 + wv;
  float acc0 = 0.f, acc1 = 0.f;
  const float* ap = A_T + m;
  const float* wp = W + c;
#pragma unroll 4
  for (int k = 0; k + 1 < K; k += 2) {
    acc0 = fmaf(ap[k * 64], wp[(size_t)k * N], acc0);
    acc1 = fmaf(ap[(k + 1) * 64], wp[(size_t)(k + 1) * N], acc1);
  }
  float v0 = acc0 + acc1 + bias[c];
  if (ACT) v0 = fmaxf(v0, 0.f);
  C_T[c * 64 + m] = v0;
  if (outp != nullptr) outp[(size_t)(m * TSTEP + tstep) * LATD + c] = v0;
}
__global__ void fb_gru(const float* __restrict__ xT, const float* __restrict__ hT,
                       const float* __restrict__ Wih, const float* __restrict__ Whh,
                       const float* __restrict__ bih, const float* __restrict__ bhh,
                       float* __restrict__ hnT) {
  const int m = threadIdx.x & 63;
  const int wv = threadIdx.x >> 6;
  const int c = blockIdx.x * 4 + wv;
  float racc = 0, zacc = 0, iacc = 0, nacc = 0;
  const float* xp = xT + m;
  const float* hp = hT + m;
  const float* wi = Wih + c;
  const float* wh = Whh + c;
#pragma unroll 2
  for (int k = 0; k < 1024; ++k) {
    float a = xp[k * 64];
    float h = hp[k * 64];
    const float* wik = wi + (size_t)k * 3072;
    const float* whk = wh + (size_t)k * 3072;
    racc = fmaf(a, wik[0], racc); racc = fmaf(h, whk[0], racc);
    zacc = fmaf(a, wik[1024], zacc); zacc = fmaf(h, whk[1024], zacc);
    iacc = fmaf(a, wik[2048], iacc);
    nacc = fmaf(h, whk[2048], nacc);
  }
  float r = 1.f / (1.f + expf(-(racc + bih[c] + bhh[c])));
  float zg = 1.f / (1.f + expf(-(zacc + bih[1024 + c] + bhh[1024 + c])));
  float nn = tanhf(iacc + bih[2048 + c] + r * (nacc + bhh[2048 + c]));
  hnT[c * 64 + m] = (1.f - zg) * nn + zg * hT[c * 64 + m];
}

extern "C" void kernel_launch(void* const* d_in, const int* in_sizes, int n_in,
                              void* d_out, int out_size, void* d_ws, size_t ws_size,
                              hipStream_t stream) {
  const float* z_start = (const float*)d_in[0];
  const float* w1 = (const float*)d_in[2];
  const float* b1 = (const float*)d_in[3];
  const float* w2 = (const float*)d_in[4];
  const float* b2 = (const float*)d_in[5];
  const float* Wv = (const float*)d_in[10];
  const float* bv = (const float*)d_in[11];
  const float* Wo = (const float*)d_in[12];
  const float* bo = (const float*)d_in[13];
  const float* Wih0 = (const float*)d_in[14];
  const float* Whh0 = (const float*)d_in[15];
  const float* bih0 = (const float*)d_in[16];
  const float* bhh0 = (const float*)d_in[17];
  const float* Wih1 = (const float*)d_in[18];
  const float* Whh1 = (const float*)d_in[19];
  const float* bih1 = (const float*)d_in[20];
  const float* bhh1 = (const float*)d_in[21];
  const float* Wh = (const float*)d_in[22];
  const float* bh = (const float*)d_in[23];
  float* out = (float*)d_out;
  float* ws = (float*)d_ws;

  // floats: 4x1572864 (fp16 wbufs) + part 1572864 (Wvo temp + h1b/h2b) +
  // 524288x2 (WhW1_h,w2_h) + 131072 (Wh_h) + 4x65536 acts + 5120 small + 1024
  const size_t need = (size_t)9312256 * 4;
  if (ws_size >= need) {
    P p;
    p.z = z_start; p.w1 = w1; p.b1 = b1; p.w2 = w2; p.b2 = b2;
    p.Wv = Wv; p.bv = bv; p.Wo = Wo; p.bo = bo;
    p.Wih0 = Wih0; p.Whh0 = Whh0; p.bih0 = bih0; p.bhh0 = bhh0;
    p.Wih1 = Wih1; p.Whh1 = Whh1; p.bih1 = bih1; p.bhh1 = bhh1;
    p.Wh = Wh; p.bh = bh; p.out = out;
    float* q = ws;
    p.Wvoihh = (__half*)q; q += 1572864;   // 1024x3072 halves
    p.Whh0h  = (__half*)q; q += 1572864;
    p.Wih1h  = (__half*)q; q += 1572864;
    p.Whh1h  = (__half*)q; q += 1572864;
    p.WhW1h  = (__half*)q; q += 524288;    // 1024x1024 halves
    p.Whh    = (__half*)q; q += 131072;    // 1024x256 halves
    p.w2h    = (__half*)q; q += 524288;
    p.part = q; q += 1572864;   // prologue Wvo temp (first 1048576 f)
    p.h1b = p.part + 1048576;   // loop-side double buffers (never overlap Wvo)
    p.h2b = p.part + 1114112;
    p.gin = q; q += 65536;
    p.h1 = q; q += 65536;       // also zT during prologue
    p.h2 = q; q += 65536;
    p.t1 = q; q += 65536;
    p.bvo = q; q += 1024;
    p.bfold = q; q += 3072;
    p.bhw1 = q; q += 1024;
    p.bar = (unsigned*)q; q += 1024;
    void* args[] = { &p };
    hipError_t e = hipLaunchCooperativeKernel((const void*)persist, dim3(256),
                                              dim3(512), args, 0, stream);
    if (e == hipSuccess) return;
  }

  // -------- fallback: verified round-2 path --------
  float* zsT = ws;
  float* vT = zsT + 16384;
  float* xaT = vT + 65536;
  float* t1T = xaT + 65536;
  float* ginT = t1T + 65536;
  float* nzT = ginT + 65536;
  float* h1T = nzT + 16384;
  float* h2T = h1T + 2 * 65536;

  fb_transpose<<<64, 256, 0, stream>>>(z_start, zsT);
  fb_gemm<1><<<256, 256, 0, stream>>>(zsT, w1, b1, t1T, 256, 1024, nullptr, 0);
  fb_gemm<0><<<256, 256, 0, stream>>>(t1T, w2, b2, h1T, 1024, 1024, nullptr, 0);
  fb_copy2<<<256, 256, 0, stream>>>(h1T, h2T, ginT);
  for (int t = 0; t < TSTEP; ++t) {
    float* h1p = h1T + (t & 1) * 65536;
    float* h1n = h1T + ((t + 1) & 1) * 65536;
    float* h2p = h2T + (t & 1) * 65536;
    float* h2n = h2T + ((t + 1) & 1) * 65536;
    fb_gemm<0><<<256, 256, 0, stream>>>(ginT, Wv, bv, vT, 1024, 1024, nullptr, 0);
    fb_gemm<0><<<256, 256, 0, stream>>>(vT, Wo, bo, xaT, 1024, 1024, nullptr, 0);
    fb_gru<<<256, 256, 0, stream>>>(xaT, h1p, Wih0, Whh0, bih0, bhh0, h1n);
    fb_gru<<<256, 256, 0, stream>>>(h1n, h2p, Wih1, Whh1, bih1, bhh1, h2n);
    fb_gemm<0><<<64, 256, 0, stream>>>(h2n, Wh, bh, nzT, 1024, 256, out, t);
    fb_gemm<1><<<256, 256, 0, stream>>>(nzT, w1, b1, t1T, 256, 1024, nullptr, 0);
    fb_gemm<1><<<256, 256, 0, stream>>>(t1T, w2, b2, ginT, 1024, 1024, nullptr, 0);
  }
}

// Round 9
// 11855.823 us; speedup vs baseline: 1.9327x; 1.9327x over previous
//
#include <hip/hip_runtime.h>
#include <hip/hip_cooperative_groups.h>
#include <hip/hip_fp16.h>

namespace cg = cooperative_groups;

#define TSTEP 128
#define LATD 256

// ---------------------------------------------------------------------------
// R16 = R12 (verified 12.29 ms) + two local changes:
//  (a) fp16 partials: same 8-slice layout/epilogue, pack2h u32 stores, aldh
//      reads. Halves the sc1 store volume drained at every barrier (19->9.6
//      MB/step) and halves combine read traffic. (R15's one sound idea,
//      isolated on the verified structure.)
//  (b) p5 register-blocked on the p6 skeleton: weights in padded 8-slot
//      groups [128][64]h, 4 ksubs x 8 cg x 16 mq, 20 acc, 2 LDS / 20 FMA
//      (was wave-broadcast 5 FMA / ~6 LDS-clk).
// R14/R15 post-mortem: full-K (384 MB/step act amplification) and 2-block/CU
// (2x sc1 streams + barrier arrivals) both amplified the fabric path ->
// reverted; structure stays R12's 256 blocks x 512 thr, 8 phases, 16-leaf
// tree barrier.
// Folds (verified R3-R15): Wvoih=(Wv@Wo)@Wih0, bfold=(bv@Wo+bo)@Wih0+bih0,
// WhW1=Wh@w1, bhw1=bh@w1+b1. Step = 8 phases.
// ---------------------------------------------------------------------------

typedef __attribute__((ext_vector_type(2))) unsigned long long u64x2;

struct P {
  const float *z, *w1, *b1, *w2, *b2, *Wv, *bv, *Wo, *bo;
  const float *Wih0, *Whh0, *bih0, *bhh0, *Wih1, *Whh1, *bih1, *bhh1, *Wh, *bh;
  float *out;
  __half *Wvoihh, *Whh0h, *Wih1h, *Whh1h, *WhW1h, *Whh, *w2h;
  float *part, *gin, *h1, *h2, *t1, *bvo, *bfold, *bhw1;
  __half *part16;  // alias of part region (fp16 partials in loop)
  unsigned *bar;   // leaves at i*32 (i<16), root at 512, flag at 544
};

__device__ __forceinline__ float ald(const float* p) {
  return __hip_atomic_load((float*)p, __ATOMIC_RELAXED, __HIP_MEMORY_SCOPE_AGENT);
}
__device__ __forceinline__ void ast(float* p, float v) {
  __hip_atomic_store(p, v, __ATOMIC_RELAXED, __HIP_MEMORY_SCOPE_AGENT);
}
__device__ __forceinline__ void ast32(unsigned* p, unsigned v) {
  __hip_atomic_store(p, v, __ATOMIC_RELAXED, __HIP_MEMORY_SCOPE_AGENT);
}
__device__ __forceinline__ unsigned long long ald64(const unsigned long long* p) {
  return __hip_atomic_load((unsigned long long*)p, __ATOMIC_RELAXED,
                           __HIP_MEMORY_SCOPE_AGENT);
}
__device__ __forceinline__ float aldh(const __half* p) {
  unsigned short v = __hip_atomic_load((unsigned short*)p, __ATOMIC_RELAXED,
                                       __HIP_MEMORY_SCOPE_AGENT);
  __half h; *(unsigned short*)&h = v;
  return __half2float(h);
}
__device__ __forceinline__ unsigned pack2h(float x, float y) {
  union { unsigned u; __half h[2]; } c;
  c.h[0] = __float2half(x); c.h[1] = __float2half(y);
  return c.u;
}

// 4 packed halves -> float4 (staging helpers).
__device__ __forceinline__ float4 h4f(unsigned long long u) {
  union { unsigned long long q; __half h[4]; } c; c.q = u;
  return make_float4(__half2float(c.h[0]), __half2float(c.h[1]),
                     __half2float(c.h[2]), __half2float(c.h[3]));
}
__device__ __forceinline__ unsigned long long f4h4(float4 v) {
  union { unsigned long long q; __half h[4]; } c;
  c.h[0] = __float2half(v.x); c.h[1] = __float2half(v.y);
  c.h[2] = __float2half(v.z); c.h[3] = __float2half(v.w);
  return c.q;
}

// Fence-free hierarchical grid barrier (R7-proven; R12 version).
__device__ __forceinline__ void fastbar(unsigned* bar, unsigned& ep) {
  ++ep;
  __atomic_signal_fence(__ATOMIC_SEQ_CST);
  __builtin_amdgcn_s_waitcnt(0);
  __atomic_signal_fence(__ATOMIC_SEQ_CST);
  __syncthreads();
  if (threadIdx.x == 0) {
    unsigned* leaf = bar + (blockIdx.x & 15u) * 32u;
    unsigned a = atomicAdd(leaf, 1u);
    if (a == ep * 16u - 1u) {
      unsigned r = atomicAdd(bar + 512, 1u);
      if (r == ep * 16u - 1u)
        __hip_atomic_store(bar + 544, ep, __ATOMIC_RELAXED, __HIP_MEMORY_SCOPE_AGENT);
    }
    while (__hip_atomic_load(bar + 544, __ATOMIC_RELAXED, __HIP_MEMORY_SCOPE_AGENT) < ep)
      __builtin_amdgcn_s_sleep(1);
  }
  __syncthreads();
}

// ---- prologue helpers (256 blocks x 512 threads; identical to R12) --------
__device__ __forceinline__ void stv(float* p, float v) { *p = v; }
__device__ __forceinline__ void stv(__half* p, float v) { *p = __float2half(v); }

template <int J, int N, int CPT, typename OT>
__device__ void matmat(const float* __restrict__ A, const float* __restrict__ B,
                       OT* __restrict__ C) {
  const int tid = threadIdx.x;
  const int r = blockIdx.x * 4 + (tid >> 7);
  const int c0 = tid & 127;
  float acc[CPT];
#pragma unroll
  for (int i = 0; i < CPT; ++i) acc[i] = 0.f;
  const float* ar = A + (size_t)r * J;
#pragma unroll 2
  for (int j = 0; j < J; ++j) {
    float av = ar[j];
    const float* br = B + (size_t)j * N + c0;
#pragma unroll
    for (int i = 0; i < CPT; ++i) acc[i] = fmaf(av, br[i * 128], acc[i]);
  }
  OT* cr = C + (size_t)r * N + c0;
#pragma unroll
  for (int i = 0; i < CPT; ++i) stv(cr + (size_t)i * 128, acc[i]);
}

__device__ void cvt_copy(const float* __restrict__ s, __half* __restrict__ d,
                         int n4) {
  for (int i = (int)(blockIdx.x * 512u + threadIdx.x); i < n4; i += 131072)
    *(unsigned long long*)(d + (size_t)i * 4) = f4h4(*(const float4*)(s + (size_t)i * 4));
}

__device__ void vecmat(const float* __restrict__ v, const float* __restrict__ M,
                       const float* __restrict__ badd, float* __restrict__ outv,
                       int J, int N, int blk0, int nblk) {
  int b = (int)blockIdx.x;
  if (b < blk0 || b >= blk0 + nblk) return;
  int gid = (b - blk0) * 512 + threadIdx.x;
  if (gid >= N) return;
  float acc = 0.f;
#pragma unroll 4
  for (int j = 0; j < J; ++j) acc = fmaf(v[j], M[(size_t)j * N + gid], acc);
  outv[gid] = acc + badd[gid];
}

__device__ void gemv1024(const float* __restrict__ A, const float* __restrict__ W,
                         const float* __restrict__ bias, int K, int relu,
                         float* __restrict__ C, float* __restrict__ C2,
                         float* __restrict__ C3, float* red) {
  const int tid = threadIdx.x;
  const int m = tid & 63, w = tid >> 6;
  const int j = w & 3, hh = w >> 2;
  const int c = blockIdx.x * 4 + j;
  const int kh = K >> 1;
  const float* a = A + m + (hh * kh) * 64;
  const float* wp = W + c + (size_t)(hh * kh) * 1024;
  float acc = 0.f;
#pragma unroll 8
  for (int k = 0; k < kh; ++k) acc = fmaf(a[k * 64], wp[(size_t)k * 1024], acc);
  if (hh) red[j * 64 + m] = acc;
  __syncthreads();
  if (!hh) {
    float v = acc + red[j * 64 + m] + bias[c];
    if (relu) v = fmaxf(v, 0.f);
    C[c * 64 + m] = v;
    if (C2) C2[c * 64 + m] = v;
    if (C3) C3[c * 64 + m] = v;
  }
  __syncthreads();
}

// ---- GRU matmul: 256 blocks = 32 col-groups(96) x 8 K-slices(256) ---------
// Identical FMA core to R12; epilogue stores fp16 (pack2h, dense u32).
__device__ __forceinline__ void gru_mm(const __half* __restrict__ Wx,
                                       const float* __restrict__ actx,
                                       const __half* __restrict__ Whm,
                                       const float* __restrict__ acth,
                                       __half* __restrict__ part16,
                                       float* __restrict__ sm) {
  const int tid = threadIdx.x;
  const int bid = blockIdx.x;
  const int g = bid >> 3, s = bid & 7;
  const int c0 = g * 96;
  const int k0 = (s & 3) * 256;
  const __half* W = (s < 4 ? Wx : Whm);
  const float* A = (s < 4 ? actx : acth) + (size_t)k0 * 64;

  // ---- stage acts (8192 dw) ----
  {
    const unsigned long long* Ab = (const unsigned long long*)A;
    unsigned long long* Sb = (unsigned long long*)sm;
#pragma unroll
    for (int i = 0; i < 16; ++i) Sb[tid + i * 512] = ald64(Ab + tid + i * 512);
  }
  // ---- stage weights fp16 -> planes (thread: k=tid>>1, 48 halves) ----
  {
    const int k = tid >> 1, hr = tid & 1;
    const unsigned long long* Wr =
        (const unsigned long long*)(W + (size_t)(k0 + k) * 3072 + c0) + hr * 12;
    unsigned long long* pa = (unsigned long long*)(sm + 16384) + k * 16 + hr * 8;
    unsigned long long* pb = (unsigned long long*)(sm + 24576) + k * 8 + hr * 4;
#pragma unroll
    for (int j = 0; j < 4; ++j) {
      unsigned long long q0 = Wr[j * 3];
      unsigned long long q1 = Wr[j * 3 + 1];
      unsigned long long q2 = Wr[j * 3 + 2];
      pa[j * 2] = q0; pa[j * 2 + 1] = q1; pb[j] = q2;
    }
  }
  __syncthreads();

  const int ksub = tid >> 7, u = tid & 127;
  const int mq = u & 15, cg = u >> 4;
  float acc[48];
#pragma unroll
  for (int j = 0; j < 48; ++j) acc[j] = 0.f;
  const float* ap = sm + (size_t)(ksub * 64) * 64 + mq * 4;
  const __half* wa = (const __half*)(sm + 16384) + (size_t)(ksub * 64) * 64 + cg * 8;
  const __half* wb = (const __half*)(sm + 24576) + (size_t)(ksub * 64) * 32 + cg * 4;
#pragma unroll 2
  for (int k = 0; k < 64; ++k) {
    float4 a4 = *(const float4*)(ap + k * 64);
    union { u64x2 v; __half h[8]; } ua;
    ua.v = *(const u64x2*)(wa + k * 64);
    union { unsigned long long v; __half h[4]; } ub;
    ub.v = *(const unsigned long long*)(wb + k * 32);
#pragma unroll
    for (int c = 0; c < 8; ++c) {
      float wf = __half2float(ua.h[c]);
      acc[c * 4 + 0] = fmaf(a4.x, wf, acc[c * 4 + 0]);
      acc[c * 4 + 1] = fmaf(a4.y, wf, acc[c * 4 + 1]);
      acc[c * 4 + 2] = fmaf(a4.z, wf, acc[c * 4 + 2]);
      acc[c * 4 + 3] = fmaf(a4.w, wf, acc[c * 4 + 3]);
    }
#pragma unroll
    for (int c = 0; c < 4; ++c) {
      float wf = __half2float(ub.h[c]);
      acc[32 + c * 4 + 0] = fmaf(a4.x, wf, acc[32 + c * 4 + 0]);
      acc[32 + c * 4 + 1] = fmaf(a4.y, wf, acc[32 + c * 4 + 1]);
      acc[32 + c * 4 + 2] = fmaf(a4.z, wf, acc[32 + c * 4 + 2]);
      acc[32 + c * 4 + 3] = fmaf(a4.w, wf, acc[32 + c * 4 + 3]);
    }
  }
  // ---- epilogue: ksubs -> LDS (part-linear), dense K-sum + fp16 store ----
  __syncthreads();   // acts/weights consumption complete
  float* red = sm;   // 4 regions x 6144 floats, layout = col_local*64 + m
  {
    float* rp = red + (size_t)ksub * 6144 + (size_t)cg * 12 * 64 + mq * 4;
#pragma unroll
    for (int c = 0; c < 8; ++c)
      *(float4*)(rp + (size_t)c * 64) =
          make_float4(acc[c * 4], acc[c * 4 + 1], acc[c * 4 + 2], acc[c * 4 + 3]);
#pragma unroll
    for (int c = 0; c < 4; ++c)
      *(float4*)(rp + (size_t)(8 + c) * 64) =
          make_float4(acc[32 + c * 4], acc[32 + c * 4 + 1],
                      acc[32 + c * 4 + 2], acc[32 + c * 4 + 3]);
  }
  __syncthreads();
  {
    __half* pbase = part16 + ((size_t)s * 3072 + c0) * 64;   // 6144 contiguous
#pragma unroll
    for (int ps5 = 0; ps5 < 6; ++ps5) {
      int idx = ps5 * 1024 + tid * 2;
      float2 a0 = *(const float2*)(red + idx);
      float2 a1 = *(const float2*)(red + 6144 + idx);
      float2 a2 = *(const float2*)(red + 12288 + idx);
      float2 a3 = *(const float2*)(red + 18432 + idx);
      float v0 = (a0.x + a1.x) + (a2.x + a3.x);
      float v1 = (a0.y + a1.y) + (a2.y + a3.y);
      ast32((unsigned*)(pbase + idx), pack2h(v0, v1));
    }
  }
}

// GRU combine: 8 fp16 K-slices (0-3 x-part, 4-7 h-part). 256 blocks, 256 thr.
__device__ __forceinline__ void gru_comb(const __half* __restrict__ part16,
                                         const float* __restrict__ bx,
                                         const float* __restrict__ bm,
                                         float* __restrict__ h) {
  const int tid = threadIdx.x, bid = blockIdx.x;
  if (tid >= 256) return;
  const int c = bid * 4 + (tid >> 6), m = tid & 63;
  float ra = 0.f, za = 0.f, ia = 0.f, na = 0.f;
#pragma unroll
  for (int s = 0; s < 8; ++s) {
    const __half* ps = part16 + (size_t)s * 3072 * 64;
    ra += aldh(ps + (size_t)c * 64 + m);
    za += aldh(ps + (size_t)(1024 + c) * 64 + m);
    float nv = aldh(ps + (size_t)(2048 + c) * 64 + m);
    if (s < 4) ia += nv; else na += nv;
  }
  float r  = 1.f / (1.f + expf(-(ra + bx[c] + bm[c])));
  float zg = 1.f / (1.f + expf(-(za + bx[1024 + c] + bm[1024 + c])));
  float nn = tanhf(ia + bx[2048 + c] + r * (na + bm[2048 + c]));
  float hp = ald(h + (size_t)c * 64 + m);
  ast(h + (size_t)c * 64 + m, (1.f - zg) * nn + zg * hp);
}

// ---- P5 (R16): register-blocked on p6 skeleton. C=1280, 32 groups(40) x 8
// K-slices(128). Weights padded [128][8 grp][8 slot]h (5 valid). 4 ksubs x
// 128 thr; ksub owns 32 k; thread 4m x 5c (20 acc). Per k: 1 b128 act +
// 1 b128 w = 2 LDS / 20 FMA. Epilogue: [4][2560] part-linear + fp16 stores.
__device__ __forceinline__ void p5_mm(const __half* __restrict__ WhW1,
                                      const __half* __restrict__ Whd,
                                      const float* __restrict__ h2,
                                      __half* __restrict__ part16,
                                      float* __restrict__ sm) {
  const int tid = threadIdx.x, bid = blockIdx.x;
  const int g = bid >> 3, s = bid & 7;
  const int c0 = g * 40;
  const int k0 = s * 128;
  const float* A = h2 + (size_t)k0 * 64;

  {  // stage acts (4096 dw)
    const unsigned long long* Ab = (const unsigned long long*)A;
    unsigned long long* Sb = (unsigned long long*)sm;
#pragma unroll
    for (int i = 0; i < 8; ++i) Sb[tid + i * 512] = ald64(Ab + tid + i * 512);
  }
  {  // stage weights: 1024 (row,grp) pairs, 5 scalar halves each, padded 8
    __half* Sw = (__half*)(sm + 8192);
#pragma unroll
    for (int r = 0; r < 2; ++r) {
      int i2 = tid + r * 512;
      int row = i2 & 127, grp = i2 >> 7;
      const int gcb = c0 + grp * 5;
      __half* dst = Sw + row * 64 + grp * 8;
#pragma unroll
      for (int j = 0; j < 5; ++j) {
        int gc = gcb + j;
        dst[j] = (gc < 1024) ? WhW1[(size_t)(k0 + row) * 1024 + gc]
                             : Whd[(size_t)(k0 + row) * 256 + (gc - 1024)];
      }
    }
  }
  __syncthreads();

  const int ksub = tid >> 7, u = tid & 127;
  const int mq = u & 15, cg = u >> 4;
  float acc[20];
#pragma unroll
  for (int j = 0; j < 20; ++j) acc[j] = 0.f;
  const float* ap = sm + (size_t)(ksub * 32) * 64 + mq * 4;
  const __half* wp = (const __half*)(sm + 8192) + (size_t)(ksub * 32) * 64 + cg * 8;
#pragma unroll 4
  for (int k = 0; k < 32; ++k) {
    float4 a4 = *(const float4*)(ap + k * 64);
    union { u64x2 v; __half h[8]; } uw;
    uw.v = *(const u64x2*)(wp + k * 64);
#pragma unroll
    for (int cc = 0; cc < 5; ++cc) {
      float wf = __half2float(uw.h[cc]);
      acc[cc * 4 + 0] = fmaf(a4.x, wf, acc[cc * 4 + 0]);
      acc[cc * 4 + 1] = fmaf(a4.y, wf, acc[cc * 4 + 1]);
      acc[cc * 4 + 2] = fmaf(a4.z, wf, acc[cc * 4 + 2]);
      acc[cc * 4 + 3] = fmaf(a4.w, wf, acc[cc * 4 + 3]);
    }
  }
  __syncthreads();
  float* red = sm;   // 4 regions x 2560 floats, layout = col_local*64 + m
  {
    float* rp = red + (size_t)ksub * 2560 + (size_t)cg * 5 * 64 + mq * 4;
#pragma unroll
    for (int cc = 0; cc < 5; ++cc)
      *(float4*)(rp + (size_t)cc * 64) =
          make_float4(acc[cc * 4], acc[cc * 4 + 1], acc[cc * 4 + 2], acc[cc * 4 + 3]);
  }
  __syncthreads();
  {
    __half* pbase = part16 + ((size_t)s * 1280 + c0) * 64;   // 2560 contiguous
#pragma unroll
    for (int ps5 = 0; ps5 < 3; ++ps5) {
      int idx = ps5 * 1024 + tid * 2;
      if (idx < 2560) {
        float2 a0 = *(const float2*)(red + idx);
        float2 a1 = *(const float2*)(red + 2560 + idx);
        float2 a2 = *(const float2*)(red + 5120 + idx);
        float2 a3 = *(const float2*)(red + 7680 + idx);
        float v0 = (a0.x + a1.x) + (a2.x + a3.x);
        float v1 = (a0.y + a1.y) + (a2.y + a3.y);
        ast32((unsigned*)(pbase + idx), pack2h(v0, v1));
      }
    }
  }
}

// P5 combine: t1 cols 0..1023 (tid<256), out cols 1024..1279 (tid 256..319).
__device__ __forceinline__ void p5b(const __half* __restrict__ part16,
                                    const float* __restrict__ bhw1,
                                    const float* __restrict__ bh,
                                    float* __restrict__ t1, float* __restrict__ out,
                                    int t) {
  const int tid = threadIdx.x, bid = blockIdx.x;
  if (tid < 256) {
    const int c = bid * 4 + (tid >> 6), m = tid & 63;
    float v = 0.f;
#pragma unroll
    for (int s = 0; s < 8; ++s) v += aldh(part16 + ((size_t)s * 1280 + c) * 64 + m);
    ast(t1 + (size_t)c * 64 + m, fmaxf(v + bhw1[c], 0.f));
  } else if (tid < 320) {
    const int m = tid - 256, c2 = bid;
    float v = 0.f;
#pragma unroll
    for (int s = 0; s < 8; ++s)
      v += aldh(part16 + ((size_t)s * 1280 + 1024 + c2) * 64 + m);
    out[(size_t)(m * TSTEP + t) * LATD + c2] = v + bh[c2];
  }
}

// P6: identical FMA core to R12; epilogue stores fp16.
__device__ __forceinline__ void p6_mm(const __half* __restrict__ w2h,
                                      const float* __restrict__ t1,
                                      __half* __restrict__ part16,
                                      float* __restrict__ sm) {
  const int tid = threadIdx.x;
  const int bid = blockIdx.x;
  const int g = bid >> 3, s = bid & 7;
  const int c0 = g * 32;
  const int k0 = s * 128;
  const float* A = t1 + (size_t)k0 * 64;

  {  // stage acts (4096 dw)
    const unsigned long long* Ab = (const unsigned long long*)A;
    unsigned long long* Sb = (unsigned long long*)sm;
#pragma unroll
    for (int i = 0; i < 8; ++i) Sb[tid + i * 512] = ald64(Ab + tid + i * 512);
  }
  {  // stage weights: 1024 8B-chunks (4 halves each)
    unsigned long long* Sw = (unsigned long long*)(sm + 8192);
#pragma unroll
    for (int i = 0; i < 2; ++i) {
      int q = tid + i * 512;
      int k = q >> 3, cq = q & 7;
      Sw[k * 8 + cq] =
          *(const unsigned long long*)(w2h + (size_t)(k0 + k) * 1024 + c0 + cq * 4);
    }
  }
  __syncthreads();

  const int ksub = tid >> 7, u = tid & 127;
  const int mq = u & 15, cg = u >> 4;
  float acc[16];
#pragma unroll
  for (int j = 0; j < 16; ++j) acc[j] = 0.f;
  const float* ap = sm + (size_t)(ksub * 32) * 64 + mq * 4;
  const __half* wp = (const __half*)(sm + 8192) + (size_t)(ksub * 32) * 32 + cg * 4;
#pragma unroll 4
  for (int k = 0; k < 32; ++k) {
    float4 a4 = *(const float4*)(ap + k * 64);
    union { unsigned long long v; __half h[4]; } ub;
    ub.v = *(const unsigned long long*)(wp + k * 32);
#pragma unroll
    for (int c = 0; c < 4; ++c) {
      float wf = __half2float(ub.h[c]);
      acc[c * 4 + 0] = fmaf(a4.x, wf, acc[c * 4 + 0]);
      acc[c * 4 + 1] = fmaf(a4.y, wf, acc[c * 4 + 1]);
      acc[c * 4 + 2] = fmaf(a4.z, wf, acc[c * 4 + 2]);
      acc[c * 4 + 3] = fmaf(a4.w, wf, acc[c * 4 + 3]);
    }
  }
  __syncthreads();
  float* red = sm;   // 4 regions x 2048 floats
  {
    float* rp = red + (size_t)ksub * 2048 + (size_t)cg * 4 * 64 + mq * 4;
#pragma unroll
    for (int c = 0; c < 4; ++c)
      *(float4*)(rp + (size_t)c * 64) =
          make_float4(acc[c * 4], acc[c * 4 + 1], acc[c * 4 + 2], acc[c * 4 + 3]);
  }
  __syncthreads();
  {
    __half* pbase = part16 + ((size_t)s * 1024 + c0) * 64;   // 2048 contiguous
#pragma unroll
    for (int ps5 = 0; ps5 < 2; ++ps5) {
      int idx = ps5 * 1024 + tid * 2;
      float2 a0 = *(const float2*)(red + idx);
      float2 a1 = *(const float2*)(red + 2048 + idx);
      float2 a2 = *(const float2*)(red + 4096 + idx);
      float2 a3 = *(const float2*)(red + 6144 + idx);
      float v0 = (a0.x + a1.x) + (a2.x + a3.x);
      float v1 = (a0.y + a1.y) + (a2.y + a3.y);
      ast32((unsigned*)(pbase + idx), pack2h(v0, v1));
    }
  }
}

__device__ __forceinline__ void p6b(const __half* __restrict__ part16,
                                    const float* __restrict__ b2,
                                    float* __restrict__ gin) {
  const int tid = threadIdx.x, bid = blockIdx.x;
  if (tid >= 256) return;
  const int c = bid * 4 + (tid >> 6), m = tid & 63;
  float v = 0.f;
#pragma unroll
  for (int s = 0; s < 8; ++s) v += aldh(part16 + ((size_t)s * 1024 + c) * 64 + m);
  ast(gin + (size_t)c * 64 + m, fmaxf(v + b2[c], 0.f));
}

__global__ __launch_bounds__(512, 1) void persist(P p) {
  cg::grid_group grid = cg::this_grid();
  // 112 KB: gru acts [256][64] f32 (16384 f) | planeA (8192 f) | planeB
  // (4096 f). Reduce reuses first 24576 f. p5: acts 8192 + w 4096 @8192;
  // reduce [4][2560] @0. p6: acts + w @8192; reduce [4][2048] @0.
  __shared__ float sm[28672];
  unsigned ep = 0;

  // ---- prologue (4 slow cg syncs flush prologue's normal stores) ----
  if (blockIdx.x == 0) {
    for (int i = threadIdx.x; i < 1024; i += 512) p.bar[i] = 0u;
  }
  if (threadIdx.x < 64) {  // z transpose -> h1 region (consumed pre-overwrite)
    int i = blockIdx.x * 64 + threadIdx.x;
    int m = i >> 8, l = i & 255;
    p.h1[l * 64 + m] = p.z[i];
  }
  matmat<1024, 1024, 8>(p.Wv, p.Wo, p.part);            // Wvo (fp32 temp)
  vecmat(p.bh, p.w1, p.b1, p.bhw1, 256, 1024, 0, 2);
  vecmat(p.bv, p.Wo, p.bo, p.bvo, 1024, 1024, 2, 2);
  cvt_copy(p.Whh0, p.Whh0h, 786432);                    // raw weights -> fp16
  cvt_copy(p.Wih1, p.Wih1h, 786432);
  cvt_copy(p.Whh1, p.Whh1h, 786432);
  cvt_copy(p.w2,   p.w2h,   262144);
  cvt_copy(p.Wh,   p.Whh,   65536);
  grid.sync();
  matmat<1024, 3072, 24>(p.part, p.Wih0, p.Wvoihh);     // Wvoih -> fp16 direct
  matmat<256, 1024, 8>(p.Wh, p.w1, p.WhW1h);            // WhW1 -> fp16 direct
  vecmat(p.bvo, p.Wih0, p.bih0, p.bfold, 1024, 3072, 0, 6);
  grid.sync();
  gemv1024(p.h1, p.w1, p.b1, 256, 1, p.t1, nullptr, nullptr, sm);
  grid.sync();
  gemv1024(p.t1, p.w2, p.b2, 1024, 0, p.h1, p.h2, p.gin, sm);
  grid.sync();

  // ---- time loop: 8 fence-free phases/step ----
  for (int t = 0; t < TSTEP; ++t) {
    gru_mm(p.Wvoihh, p.gin, p.Whh0h, p.h1, p.part16, sm); fastbar(p.bar, ep);
    gru_comb(p.part16, p.bfold, p.bhh0, p.h1);            fastbar(p.bar, ep);
    gru_mm(p.Wih1h, p.h1, p.Whh1h, p.h2, p.part16, sm);   fastbar(p.bar, ep);
    gru_comb(p.part16, p.bih1, p.bhh1, p.h2);             fastbar(p.bar, ep);
    p5_mm(p.WhW1h, p.Whh, p.h2, p.part16, sm);            fastbar(p.bar, ep);
    p5b(p.part16, p.bhw1, p.bh, p.t1, p.out, t);          fastbar(p.bar, ep);
    p6_mm(p.w2h, p.t1, p.part16, sm);                     fastbar(p.bar, ep);
    p6b(p.part16, p.b2, p.gin);                           fastbar(p.bar, ep);
  }
}

// ---------------------------------------------------------------------------
// Fallback path (round-2 verified multi-kernel, fp32 — unchanged).
// ---------------------------------------------------------------------------
__global__ void fb_transpose(const float* __restrict__ z, float* __restrict__ zT) {
  int i = blockIdx.x * 256 + threadIdx.x;
  int m = i >> 8, l = i & 255;
  zT[l * 64 + m] = z[i];
}
__global__ void fb_copy2(const float* __restrict__ s, float* __restrict__ d1,
                         float* __restrict__ d2) {
  int i = blockIdx.x * 256 + threadIdx.x;
  float v = s[i]; d1[i] = v; d2[i] = v;
}
template <int ACT>
__global__ void fb_gemm(const float* __restrict__ A_T, const float* __restrict__ W,
                        const float* __restrict__ bias, float* __restrict__ C_T,
                        int K, int N, float* __restrict__ outp, int tstep) {
  const int m = threadIdx.x & 63;
  const int wv = threadIdx.x >> 6;
  const int c = blockIdx.x * 4 + wv;
  float acc0 = 0.f, acc1 = 0.f;
  const float* ap = A_T + m;
  const float* wp = W + c;
#pragma unroll 4
  for (int k = 0; k + 1 < K; k += 2) {
    acc0 = fmaf(ap[k * 64], wp[(size_t)k * N], acc0);
    acc1 = fmaf(ap[(k + 1) * 64], wp[(size_t)(k + 1) * N], acc1);
  }
  float v0 = acc0 + acc1 + bias[c];
  if (ACT) v0 = fmaxf(v0, 0.f);
  C_T[c * 64 + m] = v0;
  if (outp != nullptr) outp[(size_t)(m * TSTEP + tstep) * LATD + c] = v0;
}
__global__ void fb_gru(const float* __restrict__ xT, const float* __restrict__ hT,
                       const float* __restrict__ Wih, const float* __restrict__ Whh,
                       const float* __restrict__ bih, const float* __restrict__ bhh,
                       float* __restrict__ hnT) {
  const int m = threadIdx.x & 63;
  const int wv = threadIdx.x >> 6;
  const int c = blockIdx.x * 4 + wv;
  float racc = 0, zacc = 0, iacc = 0, nacc = 0;
  const float* xp = xT + m;
  const float* hp = hT + m;
  const float* wi = Wih + c;
  const float* wh = Whh + c;
#pragma unroll 2
  for (int k = 0; k < 1024; ++k) {
    float a = xp[k * 64];
    float h = hp[k * 64];
    const float* wik = wi + (size_t)k * 3072;
    const float* whk = wh + (size_t)k * 3072;
    racc = fmaf(a, wik[0], racc); racc = fmaf(h, whk[0], racc);
    zacc = fmaf(a, wik[1024], zacc); zacc = fmaf(h, whk[1024], zacc);
    iacc = fmaf(a, wik[2048], iacc);
    nacc = fmaf(h, whk[2048], nacc);
  }
  float r = 1.f / (1.f + expf(-(racc + bih[c] + bhh[c])));
  float zg = 1.f / (1.f + expf(-(zacc + bih[1024 + c] + bhh[1024 + c])));
  float nn = tanhf(iacc + bih[2048 + c] + r * (nacc + bhh[2048 + c]));
  hnT[c * 64 + m] = (1.f - zg) * nn + zg * hT[c * 64 + m];
}

extern "C" void kernel_launch(void* const* d_in, const int* in_sizes, int n_in,
                              void* d_out, int out_size, void* d_ws, size_t ws_size,
                              hipStream_t stream) {
  const float* z_start = (const float*)d_in[0];
  const float* w1 = (const float*)d_in[2];
  const float* b1 = (const float*)d_in[3];
  const float* w2 = (const float*)d_in[4];
  const float* b2 = (const float*)d_in[5];
  const float* Wv = (const float*)d_in[10];
  const float* bv = (const float*)d_in[11];
  const float* Wo = (const float*)d_in[12];
  const float* bo = (const float*)d_in[13];
  const float* Wih0 = (const float*)d_in[14];
  const float* Whh0 = (const float*)d_in[15];
  const float* bih0 = (const float*)d_in[16];
  const float* bhh0 = (const float*)d_in[17];
  const float* Wih1 = (const float*)d_in[18];
  const float* Whh1 = (const float*)d_in[19];
  const float* bih1 = (const float*)d_in[20];
  const float* bhh1 = (const float*)d_in[21];
  const float* Wh = (const float*)d_in[22];
  const float* bh = (const float*)d_in[23];
  float* out = (float*)d_out;
  float* ws = (float*)d_ws;

  // floats: 4x1572864 (fp16 wbufs) + part 1572864 (Wvo fp32 temp in
  // prologue; 8x3072x64 fp16 partials in loop = 786432 f) + 524288x2
  // (WhW1_h,w2_h) + 131072 (Wh_h) + 4x65536 acts + 5120 small + 1024 bar
  const size_t need = (size_t)9312256 * 4;
  if (ws_size >= need) {
    P p;
    p.z = z_start; p.w1 = w1; p.b1 = b1; p.w2 = w2; p.b2 = b2;
    p.Wv = Wv; p.bv = bv; p.Wo = Wo; p.bo = bo;
    p.Wih0 = Wih0; p.Whh0 = Whh0; p.bih0 = bih0; p.bhh0 = bhh0;
    p.Wih1 = Wih1; p.Whh1 = Whh1; p.bih1 = bih1; p.bhh1 = bhh1;
    p.Wh = Wh; p.bh = bh; p.out = out;
    float* q = ws;
    p.Wvoihh = (__half*)q; q += 1572864;   // 1024x3072 halves
    p.Whh0h  = (__half*)q; q += 1572864;
    p.Wih1h  = (__half*)q; q += 1572864;
    p.Whh1h  = (__half*)q; q += 1572864;
    p.WhW1h  = (__half*)q; q += 524288;    // 1024x1024 halves
    p.Whh    = (__half*)q; q += 131072;    // 1024x256 halves
    p.w2h    = (__half*)q; q += 524288;
    p.part = q; q += 1572864;   // Wvo fp32 temp in prologue; fp16 parts loop
    p.part16 = (__half*)p.part;
    p.gin = q; q += 65536;
    p.h1 = q; q += 65536;       // also zT during prologue
    p.h2 = q; q += 65536;
    p.t1 = q; q += 65536;
    p.bvo = q; q += 1024;
    p.bfold = q; q += 3072;
    p.bhw1 = q; q += 1024;
    p.bar = (unsigned*)q; q += 1024;
    void* args[] = { &p };
    hipError_t e = hipLaunchCooperativeKernel((const void*)persist, dim3(256),
                                              dim3(512), args, 0, stream);
    if (e == hipSuccess) return;
  }

  // -------- fallback: verified round-2 path --------
  float* zsT = ws;
  float* vT = zsT + 16384;
  float* xaT = vT + 65536;
  float* t1T = xaT + 65536;
  float* ginT = t1T + 65536;
  float* nzT = ginT + 65536;
  float* h1T = nzT + 16384;
  float* h2T = h1T + 2 * 65536;

  fb_transpose<<<64, 256, 0, stream>>>(z_start, zsT);
  fb_gemm<1><<<256, 256, 0, stream>>>(zsT, w1, b1, t1T, 256, 1024, nullptr, 0);
  fb_gemm<0><<<256, 256, 0, stream>>>(t1T, w2, b2, h1T, 1024, 1024, nullptr, 0);
  fb_copy2<<<256, 256, 0, stream>>>(h1T, h2T, ginT);
  for (int t = 0; t < TSTEP; ++t) {
    float* h1p = h1T + (t & 1) * 65536;
    float* h1n = h1T + ((t + 1) & 1) * 65536;
    float* h2p = h2T + (t & 1) * 65536;
    float* h2n = h2T + ((t + 1) & 1) * 65536;
    fb_gemm<0><<<256, 256, 0, stream>>>(ginT, Wv, bv, vT, 1024, 1024, nullptr, 0);
    fb_gemm<0><<<256, 256, 0, stream>>>(vT, Wo, bo, xaT, 1024, 1024, nullptr, 0);
    fb_gru<<<256, 256, 0, stream>>>(xaT, h1p, Wih0, Whh0, bih0, bhh0, h1n);
    fb_gru<<<256, 256, 0, stream>>>(h1n, h2p, Wih1, Whh1, bih1, bhh1, h2n);
    fb_gemm<0><<<64, 256, 0, stream>>>(h2n, Wh, bh, nzT, 1024, 256, out, t);
    fb_gemm<1><<<256, 256, 0, stream>>>(nzT, w1, b1, t1T, 256, 1024, nullptr, 0);
    fb_gemm<1><<<256, 256, 0, stream>>>(t1T, w2, b2, ginT, 1024, 1024, nullptr, 0);
  }
}